// Round 3
// baseline (1133.557 us; speedup 1.0000x reference)
//
#include <hip/hip_runtime.h>
#include <hip/hip_bf16.h>
#include <cmath>

typedef _Float16 f16;
typedef __attribute__((ext_vector_type(4))) _Float16 f16x4;
typedef __attribute__((ext_vector_type(8))) _Float16 f16x8;
typedef __attribute__((ext_vector_type(4))) float f32x4;

__device__ inline void gload_lds16(const f16* g, f16* l) {
  __builtin_amdgcn_global_load_lds(
      (const __attribute__((address_space(1))) unsigned int*)g,
      (__attribute__((address_space(3))) unsigned int*)l, 16, 0, 0);
}

// ---------------- f32 -> f16 convert (vectorized, grid-stride) ----------------
__global__ __launch_bounds__(256) void cvt_f32_f16(const float* __restrict__ in,
                                                   f16* __restrict__ out, long n) {
  long stride = (long)gridDim.x * 256 * 8;
  for (long i = ((long)blockIdx.x * 256 + threadIdx.x) * 8; i < n; i += stride) {
    float4 a = *(const float4*)(in + i);
    float4 b = *(const float4*)(in + i + 4);
    f16x8 o;
    o[0] = (f16)a.x; o[1] = (f16)a.y; o[2] = (f16)a.z; o[3] = (f16)a.w;
    o[4] = (f16)b.x; o[5] = (f16)b.y; o[6] = (f16)b.z; o[7] = (f16)b.w;
    *(f16x8*)(out + i) = o;
  }
}

// ------------- transpose + convert: out[c][r] = in[r][c], batched z -----------
__global__ __launch_bounds__(256) void transpose_cvt(const float* __restrict__ in,
                                                     f16* __restrict__ out,
                                                     int R, int C, long sIn, long sOut) {
  in  += (long)blockIdx.z * sIn;
  out += (long)blockIdx.z * sOut;
  __shared__ f16 t[32][34];
  const int tx = threadIdx.x, ty = threadIdx.y;
  const int c0 = blockIdx.x * 32, r0 = blockIdx.y * 32;
  #pragma unroll
  for (int j = 0; j < 32; j += 8)
    t[ty + j][tx] = (f16)in[(long)(r0 + ty + j) * C + (c0 + tx)];
  __syncthreads();
  #pragma unroll
  for (int j = 0; j < 32; j += 8)
    out[(long)(c0 + ty + j) * R + (r0 + tx)] = t[tx][ty + j];
}

// ============ 256x256 NT GEMM, BK=64, 8-phase counted-vmcnt schedule ==========
// C = act(A1*B1^T [+ A2*B2^T] + bias). A [M,K] row-major, BT [N,K] row-major.
// 8 waves (2M x 4N), per-wave 128x64 out. LDS 128KB dbuf, chunk-XOR swizzle.
// 1D grid with XCD-aware bijective swizzle (nwg % 8 == 0), gx/gy are log2.
#define MM16(AF, BF, MB)                                                        \
  do {                                                                          \
    __builtin_amdgcn_s_setprio(1);                                              \
    _Pragma("unroll") for (int m_ = 0; m_ < 4; ++m_)                            \
        _Pragma("unroll") for (int n_ = 0; n_ < 4; ++n_)                        \
            acc[(MB) + m_][n_] = __builtin_amdgcn_mfma_f32_16x16x32_f16(        \
                (AF)[m_], (BF)[n_], acc[(MB) + m_][n_], 0, 0, 0);               \
    __builtin_amdgcn_s_setprio(0);                                              \
  } while (0)

#define PHASE_SYNC()                                                            \
  do {                                                                          \
    __builtin_amdgcn_s_barrier();                                               \
    asm volatile("s_waitcnt lgkmcnt(0)" ::: "memory");                          \
    __builtin_amdgcn_sched_barrier(0);                                          \
  } while (0)

template <int ACT, bool DUAL, bool WRITE_T>
__global__ __launch_bounds__(512, 2) void gemm256(
    const f16* __restrict__ A1, int lda1,
    const f16* __restrict__ B1, int ldb1, int k1,
    const f16* __restrict__ A2, int lda2,
    const f16* __restrict__ B2, int ldb2, int k2,
    const float* __restrict__ bias, const float* __restrict__ alpha,
    f16* __restrict__ C, int ldc, f16* __restrict__ CT,
    long sA, long sB, long sC, int gxs, int gys, int nwg) {
  __shared__ __align__(16) f16 As[2][16384];  // [256 rows][64 k], chunk-XOR swizzled
  __shared__ __align__(16) f16 Bs[2][16384];
  // XCD-aware bijective remap: contiguous lid chunk per XCD
  const int wg = blockIdx.x;
  const int lid = (wg & 7) * (nwg >> 3) + (wg >> 3);
  const int bx = lid & ((1 << gxs) - 1);
  const int by = (lid >> gxs) & ((1 << gys) - 1);
  const int z = lid >> (gxs + gys);

  const int tid = threadIdx.x;
  const f16* a1 = A1 + (long)z * sA;
  const f16* b1 = B1 + (long)z * sB;
  f16* pC = C + (long)z * sC;
  const int m0 = bx * 256, n0 = by * 256;
  const int lane = tid & 63, w = tid >> 6;
  const int wr = w >> 2, wc = w & 3;  // wave grid 2 (M) x 4 (N)
  const int lrow = lane & 15, kg = lane >> 4;
  const int NT1 = k1 >> 6;
  const int NT = NT1 + (DUAL ? (k2 >> 6) : 0);

  // staging: thread covers row (tid>>3)+j*64, LDS chunk tid&7; global chunk
  // pre-swizzled so LDS slot (row,c) holds global chunk c^(row&7).
  const int srow = tid >> 3;
  const int cg = (tid & 7) ^ (srow & 7);
  const int ldst = (tid & 448) * 8;  // wave-uniform LDS dest part (elems)

  // frag-read swizzle: row&7 == lrow&7
  const int swz = lrow & 7;
  const int ac0 = (kg ^ swz) * 8;        // K-step 0 chunk offset (elems)
  const int ac1 = ((4 + kg) ^ swz) * 8;  // K-step 1
  const int arow = wr * 128 + lrow;
  const int brow = wc * 64 + lrow;

  f32x4 acc[8][4] = {};
  int bs = 0;

  auto stageA = [&](int kt) {
    const f16* Ab; int la, kk;
    if (!DUAL || kt < NT1) { Ab = a1; la = lda1; kk = kt << 6; }
    else { Ab = A2; la = lda2; kk = (kt - NT1) << 6; }
    const int b = kt & 1;
    #pragma unroll
    for (int j = 0; j < 4; ++j)
      gload_lds16(Ab + (long)(m0 + srow + j * 64) * la + kk + cg * 8,
                  &As[b][j * 4096 + ldst]);
  };
  auto stageB = [&](int kt) {
    const f16* Bb; int lb, kk;
    if (!DUAL || kt < NT1) { Bb = b1; lb = ldb1; kk = kt << 6; }
    else { Bb = B2; lb = ldb2; kk = (kt - NT1) << 6; }
    const int b = kt & 1;
    #pragma unroll
    for (int j = 0; j < 4; ++j)
      gload_lds16(Bb + (long)(n0 + srow + j * 64) * lb + kk + cg * 8,
                  &Bs[b][j * 4096 + ldst]);
  };
  auto rdB = [&](f16x8* bf, int ac) {
    #pragma unroll
    for (int n = 0; n < 4; ++n)
      bf[n] = *(const f16x8*)&Bs[bs][(brow + n * 16) * 64 + ac];
  };
  auto rdA = [&](f16x8* af, int mo, int ac) {
    #pragma unroll
    for (int m = 0; m < 4; ++m)
      af[m] = *(const f16x8*)&As[bs][(arow + mo + m * 16) * 64 + ac];
  };

  // prologue: A(0), B(0), B(1); A(1) is issued in tile 0 phase 0
  stageA(0); stageB(0); stageB(1);
  asm volatile("s_waitcnt vmcnt(4)" ::: "memory");  // A0,B0 landed (B1 may pend)
  __builtin_amdgcn_s_barrier();

  for (int t = 0; t < NT; ++t) {
    bs = t & 1;
    f16x8 bf0[4], bf1[4], af[4];
    // ---- phase 0: quadrant (m 0-3, kk0); prefetch A(t+1)
    if (t + 1 < NT) stageA(t + 1);
    rdB(bf0, ac0); rdA(af, 0, ac0);
    PHASE_SYNC();
    MM16(af, bf0, 0);
    __builtin_amdgcn_s_barrier();
    // ---- phase 1: quadrant (m 0-3, kk1)
    rdB(bf1, ac1); rdA(af, 0, ac1);
    PHASE_SYNC();
    MM16(af, bf1, 0);
    __builtin_amdgcn_s_barrier();
    // ---- phase 2: quadrant (m 4-7, kk0); B buffer released -> prefetch B(t+2)
    if (t + 2 < NT) stageB(t + 2);
    rdA(af, 64, ac0);
    PHASE_SYNC();
    MM16(af, bf0, 4);
    __builtin_amdgcn_s_barrier();
    // ---- phase 3: quadrant (m 4-7, kk1)
    rdA(af, 64, ac1);
    PHASE_SYNC();
    MM16(af, bf1, 4);
    __builtin_amdgcn_s_barrier();
    // ---- tile boundary: next tile's A,B must have landed (counted, not 0)
    if (t + 1 < NT) {
      if (t + 2 < NT)
        asm volatile("s_waitcnt vmcnt(4)" ::: "memory");  // only B(t+2) may pend
      else
        asm volatile("s_waitcnt vmcnt(0)" ::: "memory");
      __builtin_amdgcn_s_barrier();
    }
  }

  // epilogue: C/D frag layout col=lane&15, row=(lane>>4)*4+r
  #pragma unroll
  for (int n = 0; n < 4; ++n) {
    const int gn = n0 + wc * 64 + n * 16 + lrow;
    const float bv = bias ? bias[gn] : 0.0f;
    const float av = (ACT == 2) ? alpha[gn] : 0.0f;
    #pragma unroll
    for (int m = 0; m < 8; ++m) {
      const int rg0 = m0 + wr * 128 + m * 16 + kg * 4;
      f16 tv[4];
      #pragma unroll
      for (int r = 0; r < 4; ++r) {
        float v = acc[m][n][r] + bv;
        if (ACT == 1) v = fmaxf(v, 0.0f);
        if (ACT == 2) v = (v > 0.0f) ? v : av * v;
        const f16 h = (f16)v;
        tv[r] = h;
        pC[(long)(rg0 + r) * ldc + gn] = h;
      }
      if (WRITE_T) {
        const int b = rg0 >> 10, node = rg0 & 1023;
        f16x4 pk;
        pk[0] = tv[0]; pk[1] = tv[1]; pk[2] = tv[2]; pk[3] = tv[3];
        *(f16x4*)&CT[((long)b * ldc + gn) * 1024 + node] = pk;
      }
    }
  }
}

// -------- final: logits = p @ Wc2 + bc2 ; out = log_softmax (fp32) ------------
__global__ __launch_bounds__(256) void logits_lsm(const f16* __restrict__ hc,
                                                  const float* __restrict__ Wc2,
                                                  const float* __restrict__ bc2,
                                                  float* __restrict__ out) {
  __shared__ float w[512];
  __shared__ float bb[2];
  const int t = threadIdx.x;
  w[t] = Wc2[t];
  w[t + 256] = Wc2[t + 256];
  if (t < 2) bb[t] = bc2[t];
  __syncthreads();
  const long row = (long)blockIdx.x * 256 + t;
  const f16* hr = hc + row * 256;
  float l0 = 0.f, l1 = 0.f;
  #pragma unroll 4
  for (int d0 = 0; d0 < 256; d0 += 8) {
    f16x8 v = *(const f16x8*)(hr + d0);
    #pragma unroll
    for (int j = 0; j < 8; ++j) {
      const float p = (float)v[j];
      l0 += p * w[(d0 + j) * 2];
      l1 += p * w[(d0 + j) * 2 + 1];
    }
  }
  l0 += bb[0];
  l1 += bb[1];
  const float mx = fmaxf(l0, l1);
  const float lse = mx + logf(expf(l0 - mx) + expf(l1 - mx));
  out[row * 2] = l0 - lse;
  out[row * 2 + 1] = l1 - lse;
}

extern "C" void kernel_launch(void* const* d_in, const int* in_sizes, int n_in,
                              void* d_out, int out_size, void* d_ws, size_t ws_size,
                              hipStream_t stream) {
  const float* x     = (const float*)d_in[0];   // [64,1024,256]
  const float* adj   = (const float*)d_in[1];   // [64,1024,1024]
  const float* W1    = (const float*)d_in[2];   // [512,512]
  const float* b1    = (const float*)d_in[3];
  const float* W2    = (const float*)d_in[4];   // [1024,512]
  const float* b2    = (const float*)d_in[5];
  const float* W3    = (const float*)d_in[6];   // [1024,256]
  const float* b3    = (const float*)d_in[7];
  const float* W4    = (const float*)d_in[8];   // [512,256]
  const float* b4    = (const float*)d_in[9];
  const float* Wc1   = (const float*)d_in[10];  // [256,256]
  const float* bc1   = (const float*)d_in[11];
  const float* alpha = (const float*)d_in[12];
  const float* Wc2   = (const float*)d_in[13];  // [256,2]
  const float* bc2   = (const float*)d_in[14];
  float* out = (float*)d_out;

  char* ws = (char*)d_ws;
  f16* adjB = (f16*)(ws + 0L);          // 134217728 B
  f16* xN   = (f16*)(ws + 134217728L);  // 33554432 B
  f16* xT   = (f16*)(ws + 167772160L);  // 33554432 B
  f16* agg  = (f16*)(ws + 201326592L);  // 67108864 B
  f16* hAN  = (f16*)(ws + 268435456L);  // 67108864 B  (h1, h3, hc)
  f16* hAT  = (f16*)(ws + 335544320L);  // 67108864 B  (h1T, h3T)
  f16* hBN  = (f16*)(ws + 402653184L);  // 67108864 B  (h2, h4)
  f16* hBT  = (f16*)(ws + 469762048L);  // 67108864 B  (h2T)
  f16* WT1  = (f16*)(ws + 536870912L);  // [512][512]
  f16* WT2  = (f16*)(ws + 537395200L);  // [512][1024]
  f16* WT3  = (f16*)(ws + 538443776L);  // [256][1024]
  f16* WT4  = (f16*)(ws + 538968064L);  // [256][512]
  f16* WTc1 = (f16*)(ws + 539230208L);  // [256][256]
  if (ws_size < (size_t)539361280L) return;

  const dim3 tb(32, 8, 1);

  cvt_f32_f16<<<2048, 256, 0, stream>>>(adj, adjB, 64L * 1024 * 1024);
  cvt_f32_f16<<<1024, 256, 0, stream>>>(x, xN, 64L * 1024 * 256);
  transpose_cvt<<<dim3(8, 32, 64), tb, 0, stream>>>(x, xT, 1024, 256, 1024L * 256, 256L * 1024);
  transpose_cvt<<<dim3(16, 16, 1), tb, 0, stream>>>(W1, WT1, 512, 512, 0, 0);
  transpose_cvt<<<dim3(16, 32, 1), tb, 0, stream>>>(W2, WT2, 1024, 512, 0, 0);
  transpose_cvt<<<dim3(8, 32, 1), tb, 0, stream>>>(W3, WT3, 1024, 256, 0, 0);
  transpose_cvt<<<dim3(8, 16, 1), tb, 0, stream>>>(W4, WT4, 512, 256, 0, 0);
  transpose_cvt<<<dim3(8, 8, 1), tb, 0, stream>>>(Wc1, WTc1, 256, 256, 0, 0);

  // ---- L1: agg = adj @ x   (grid gx=4, gy=1, gz=64 -> nwg=256)
  gemm256<0, false, false><<<256, 512, 0, stream>>>(
      adjB, 1024, xT, 1024, 1024,
      nullptr, 0, nullptr, 0, 0,
      nullptr, nullptr, agg, 256, nullptr,
      1024L * 1024, 256L * 1024, 1024L * 256, 2, 0, 256);
  // h1 = relu(x@W1t + agg@W1b + b1)   (gx=256, gy=2 -> nwg=512)
  gemm256<1, true, true><<<512, 512, 0, stream>>>(
      xN, 256, WT1, 512, 256,
      agg, 256, WT1 + 256, 512, 256,
      b1, nullptr, hAN, 512, hAT, 0, 0, 0, 8, 1, 512);

  // ---- L2
  gemm256<0, false, false><<<512, 512, 0, stream>>>(
      adjB, 1024, hAT, 1024, 1024,
      nullptr, 0, nullptr, 0, 0,
      nullptr, nullptr, agg, 512, nullptr,
      1024L * 1024, 512L * 1024, 1024L * 512, 2, 1, 512);
  gemm256<1, true, true><<<512, 512, 0, stream>>>(
      hAN, 512, WT2, 1024, 512,
      agg, 512, WT2 + 512, 1024, 512,
      b2, nullptr, hBN, 512, hBT, 0, 0, 0, 8, 1, 512);

  // ---- L3
  gemm256<0, false, false><<<512, 512, 0, stream>>>(
      adjB, 1024, hBT, 1024, 1024,
      nullptr, 0, nullptr, 0, 0,
      nullptr, nullptr, agg, 512, nullptr,
      1024L * 1024, 512L * 1024, 1024L * 512, 2, 1, 512);
  gemm256<1, true, true><<<256, 512, 0, stream>>>(
      hBN, 512, WT3, 1024, 512,
      agg, 512, WT3 + 512, 1024, 512,
      b3, nullptr, hAN, 256, hAT, 0, 0, 0, 8, 0, 256);

  // ---- L4
  gemm256<0, false, false><<<256, 512, 0, stream>>>(
      adjB, 1024, hAT, 1024, 1024,
      nullptr, 0, nullptr, 0, 0,
      nullptr, nullptr, agg, 256, nullptr,
      1024L * 1024, 256L * 1024, 1024L * 256, 2, 0, 256);
  gemm256<1, true, false><<<256, 512, 0, stream>>>(
      hAN, 256, WT4, 512, 256,
      agg, 256, WT4 + 256, 512, 256,
      b4, nullptr, hBN, 256, nullptr, 0, 0, 0, 8, 0, 256);

  // ---- classifier
  gemm256<2, false, false><<<256, 512, 0, stream>>>(
      hBN, 256, WTc1, 256, 256,
      nullptr, 0, nullptr, 0, 0,
      bc1, alpha, hAN, 256, nullptr, 0, 0, 0, 8, 0, 256);

  logits_lsm<<<256, 256, 0, stream>>>(hAN, Wc2, bc2, out);
}

// Round 4
// 1120.753 us; speedup vs baseline: 1.0114x; 1.0114x over previous
//
#include <hip/hip_runtime.h>
#include <hip/hip_bf16.h>
#include <cmath>

typedef _Float16 f16;
typedef __attribute__((ext_vector_type(4))) _Float16 f16x4;
typedef __attribute__((ext_vector_type(8))) _Float16 f16x8;
typedef __attribute__((ext_vector_type(4))) float f32x4;

__device__ inline void gload_lds16(const f16* g, f16* l) {
  __builtin_amdgcn_global_load_lds(
      (const __attribute__((address_space(1))) unsigned int*)g,
      (__attribute__((address_space(3))) unsigned int*)l, 16, 0, 0);
}

// ---------------- f32 -> f16 convert (vectorized, grid-stride) ----------------
__global__ __launch_bounds__(256) void cvt_f32_f16(const float* __restrict__ in,
                                                   f16* __restrict__ out, long n) {
  long stride = (long)gridDim.x * 256 * 8;
  for (long i = ((long)blockIdx.x * 256 + threadIdx.x) * 8; i < n; i += stride) {
    float4 a = *(const float4*)(in + i);
    float4 b = *(const float4*)(in + i + 4);
    f16x8 o;
    o[0] = (f16)a.x; o[1] = (f16)a.y; o[2] = (f16)a.z; o[3] = (f16)a.w;
    o[4] = (f16)b.x; o[5] = (f16)b.y; o[6] = (f16)b.z; o[7] = (f16)b.w;
    *(f16x8*)(out + i) = o;
  }
}

// ------------- transpose + convert: out[c][r] = in[r][c], batched z -----------
__global__ __launch_bounds__(256) void transpose_cvt(const float* __restrict__ in,
                                                     f16* __restrict__ out,
                                                     int R, int C, long sIn, long sOut) {
  in  += (long)blockIdx.z * sIn;
  out += (long)blockIdx.z * sOut;
  __shared__ f16 t[32][34];
  const int tx = threadIdx.x, ty = threadIdx.y;
  const int c0 = blockIdx.x * 32, r0 = blockIdx.y * 32;
  #pragma unroll
  for (int j = 0; j < 32; j += 8)
    t[ty + j][tx] = (f16)in[(long)(r0 + ty + j) * C + (c0 + tx)];
  __syncthreads();
  #pragma unroll
  for (int j = 0; j < 32; j += 8)
    out[(long)(c0 + ty + j) * R + (r0 + tx)] = t[tx][ty + j];
}

// ----- fused x prep: read fp32 x once, emit xN (row-major f16) + xT (f16) -----
__global__ __launch_bounds__(256) void xprep(const float* __restrict__ in,
                                             f16* __restrict__ outN,
                                             f16* __restrict__ outT,
                                             int R, int C, long sIn) {
  in   += (long)blockIdx.z * sIn;
  outN += (long)blockIdx.z * sIn;          // same element count per batch
  outT += (long)blockIdx.z * sIn;
  __shared__ f16 t[32][34];
  const int tx = threadIdx.x, ty = threadIdx.y;
  const int c0 = blockIdx.x * 32, r0 = blockIdx.y * 32;
  #pragma unroll
  for (int j = 0; j < 32; j += 8) {
    const f16 v = (f16)in[(long)(r0 + ty + j) * C + (c0 + tx)];
    t[ty + j][tx] = v;
    outN[(long)(r0 + ty + j) * C + (c0 + tx)] = v;
  }
  __syncthreads();
  #pragma unroll
  for (int j = 0; j < 32; j += 8)
    outT[(long)(c0 + ty + j) * R + (r0 + tx)] = t[tx][ty + j];
}

// ======== 256x256 NT GEMM, BK=64, deep prefetch (A 3-buf / B 2-buf) ==========
// C = act(A1*B1^T [+ A2*B2^T] + bias). A [M,K] row-major, BT [N,K] row-major.
// 8 waves (2M x 4N), per-wave 128x64 out. LDS 160KB: As[3]+Bs[2], chunk-XOR swz.
// A(t+2) issued at t.ph0 (8-phase lead), B(t+2) at t.ph2 (6-phase lead).
// by-first lid decode for L2 A-panel pairing; XCD-contiguous chunks.
#define MM16(AF, BF, MB)                                                        \
  do {                                                                          \
    __builtin_amdgcn_s_setprio(1);                                              \
    _Pragma("unroll") for (int m_ = 0; m_ < 4; ++m_)                            \
        _Pragma("unroll") for (int n_ = 0; n_ < 4; ++n_)                        \
            acc[(MB) + m_][n_] = __builtin_amdgcn_mfma_f32_16x16x32_f16(        \
                (AF)[m_], (BF)[n_], acc[(MB) + m_][n_], 0, 0, 0);               \
    __builtin_amdgcn_s_setprio(0);                                              \
  } while (0)

#define PHASE_SYNC()                                                            \
  do {                                                                          \
    __builtin_amdgcn_s_barrier();                                               \
    asm volatile("s_waitcnt lgkmcnt(0)" ::: "memory");                          \
    __builtin_amdgcn_sched_barrier(0);                                          \
  } while (0)

template <int ACT, bool DUAL, bool WRITE_T>
__global__ __launch_bounds__(512, 2) void gemm256(
    const f16* __restrict__ A1, int lda1,
    const f16* __restrict__ B1, int ldb1, int k1,
    const f16* __restrict__ A2, int lda2,
    const f16* __restrict__ B2, int ldb2, int k2,
    const float* __restrict__ bias, const float* __restrict__ alpha,
    f16* __restrict__ C, int ldc, f16* __restrict__ CT,
    long sA, long sB, long sC, int gxs, int gys, int nwg) {
  __shared__ __align__(16) f16 As[3][16384];  // 96 KB: [256 rows][64 k] each
  __shared__ __align__(16) f16 Bs[2][16384];  // 64 KB
  // XCD-aware bijective remap, by (inner) first for A-panel L2 pairing
  const int wg = blockIdx.x;
  const int lid = (wg & 7) * (nwg >> 3) + (wg >> 3);
  const int by = lid & ((1 << gys) - 1);
  const int bx = (lid >> gys) & ((1 << gxs) - 1);
  const int z = lid >> (gxs + gys);

  const int tid = threadIdx.x;
  const f16* a1 = A1 + (long)z * sA;
  const f16* b1 = B1 + (long)z * sB;
  f16* pC = C + (long)z * sC;
  const int m0 = bx * 256, n0 = by * 256;
  const int lane = tid & 63, w = tid >> 6;
  const int wr = w >> 2, wc = w & 3;  // wave grid 2 (M) x 4 (N)
  const int lrow = lane & 15, kg = lane >> 4;
  const int NT1 = k1 >> 6;
  const int NT = NT1 + (DUAL ? (k2 >> 6) : 0);

  // staging: thread covers row (tid>>3)+j*64, LDS chunk tid&7; global chunk
  // pre-swizzled so LDS slot (row,c) holds global chunk c^(row&7).
  const int srow = tid >> 3;
  const int cg = (tid & 7) ^ (srow & 7);
  const int ldst = (tid & 448) * 8;  // wave-uniform LDS dest part (elems)

  // frag-read swizzle: row&7 == lrow&7
  const int swz = lrow & 7;
  const int ac0 = (kg ^ swz) * 8;        // K-step 0 chunk offset (elems)
  const int ac1 = ((4 + kg) ^ swz) * 8;  // K-step 1
  const int arow = wr * 128 + lrow;
  const int brow = wc * 64 + lrow;

  f32x4 acc[8][4] = {};

  auto stageA = [&](int kt, int buf) {
    const f16* Ab; int la, kk;
    if (!DUAL || kt < NT1) { Ab = a1; la = lda1; kk = kt << 6; }
    else { Ab = A2; la = lda2; kk = (kt - NT1) << 6; }
    #pragma unroll
    for (int j = 0; j < 4; ++j)
      gload_lds16(Ab + (long)(m0 + srow + j * 64) * la + kk + cg * 8,
                  &As[buf][j * 4096 + ldst]);
  };
  auto stageB = [&](int kt) {
    const f16* Bb; int lb, kk;
    if (!DUAL || kt < NT1) { Bb = b1; lb = ldb1; kk = kt << 6; }
    else { Bb = B2; lb = ldb2; kk = (kt - NT1) << 6; }
    const int b = kt & 1;
    #pragma unroll
    for (int j = 0; j < 4; ++j)
      gload_lds16(Bb + (long)(n0 + srow + j * 64) * lb + kk + cg * 8,
                  &Bs[b][j * 4096 + ldst]);
  };

  // prologue: order A0,B0,A1,B1 so vmcnt(8) guarantees A0,B0 landed
  stageA(0, 0); stageB(0); stageA(1, 1); stageB(1);
  asm volatile("s_waitcnt vmcnt(8)" ::: "memory");
  __builtin_amdgcn_s_barrier();

  int abuf = 0;            // A buffer of tile t (t % 3)
  for (int t = 0; t < NT; ++t) {
    const int bbuf = t & 1;
    const int anext = (abuf + 2 >= 3) ? abuf - 1 : abuf + 2;  // (t+2)%3
    f16x8 bf0[4], bf1[4], af[4];
    // ---- phase 0: A(t+2) prefetch (8-phase lead); quadrant (m0-3, k0)
    if (t + 2 < NT) stageA(t + 2, anext);
    #pragma unroll
    for (int n = 0; n < 4; ++n)
      bf0[n] = *(const f16x8*)&Bs[bbuf][(brow + n * 16) * 64 + ac0];
    #pragma unroll
    for (int m = 0; m < 4; ++m)
      af[m] = *(const f16x8*)&As[abuf][(arow + m * 16) * 64 + ac0];
    PHASE_SYNC();
    MM16(af, bf0, 0);
    __builtin_amdgcn_s_barrier();
    // ---- phase 1: quadrant (m0-3, k1)
    #pragma unroll
    for (int n = 0; n < 4; ++n)
      bf1[n] = *(const f16x8*)&Bs[bbuf][(brow + n * 16) * 64 + ac1];
    #pragma unroll
    for (int m = 0; m < 4; ++m)
      af[m] = *(const f16x8*)&As[abuf][(arow + m * 16) * 64 + ac1];
    PHASE_SYNC();
    MM16(af, bf1, 0);
    __builtin_amdgcn_s_barrier();
    // ---- phase 2: B(t+2) prefetch (6-phase lead); quadrant (m4-7, k0)
    if (t + 2 < NT) stageB(t + 2);
    #pragma unroll
    for (int m = 0; m < 4; ++m)
      af[m] = *(const f16x8*)&As[abuf][(arow + 64 + m * 16) * 64 + ac0];
    PHASE_SYNC();
    MM16(af, bf0, 4);
    __builtin_amdgcn_s_barrier();
    // ---- phase 3: quadrant (m4-7, k1)
    #pragma unroll
    for (int m = 0; m < 4; ++m)
      af[m] = *(const f16x8*)&As[abuf][(arow + 64 + m * 16) * 64 + ac1];
    PHASE_SYNC();
    MM16(af, bf1, 4);
    __builtin_amdgcn_s_barrier();
    // ---- tile boundary: A(t+1),B(t+1) must have landed (counted wait)
    if (t + 1 < NT) {
      if (t + 2 < NT)
        asm volatile("s_waitcnt vmcnt(8)" ::: "memory");  // A(t+2),B(t+2) pend
      else
        asm volatile("s_waitcnt vmcnt(0)" ::: "memory");
      __builtin_amdgcn_s_barrier();
    }
    abuf = (abuf + 1 >= 3) ? 0 : abuf + 1;
  }

  // epilogue: C/D frag layout col=lane&15, row=(lane>>4)*4+r
  #pragma unroll
  for (int n = 0; n < 4; ++n) {
    const int gn = n0 + wc * 64 + n * 16 + lrow;
    const float bv = bias ? bias[gn] : 0.0f;
    const float av = (ACT == 2) ? alpha[gn] : 0.0f;
    #pragma unroll
    for (int m = 0; m < 8; ++m) {
      const int rg0 = m0 + wr * 128 + m * 16 + kg * 4;
      f16 tv[4];
      #pragma unroll
      for (int r = 0; r < 4; ++r) {
        float v = acc[m][n][r] + bv;
        if (ACT == 1) v = fmaxf(v, 0.0f);
        if (ACT == 2) v = (v > 0.0f) ? v : av * v;
        const f16 h = (f16)v;
        tv[r] = h;
        pC[(long)(rg0 + r) * ldc + gn] = h;
      }
      if (WRITE_T) {
        const int b = rg0 >> 10, node = rg0 & 1023;
        f16x4 pk;
        pk[0] = tv[0]; pk[1] = tv[1]; pk[2] = tv[2]; pk[3] = tv[3];
        *(f16x4*)&CT[((long)b * ldc + gn) * 1024 + node] = pk;
      }
    }
  }
}

// -------- final: logits = p @ Wc2 + bc2 ; out = log_softmax (fp32) ------------
__global__ __launch_bounds__(256) void logits_lsm(const f16* __restrict__ hc,
                                                  const float* __restrict__ Wc2,
                                                  const float* __restrict__ bc2,
                                                  float* __restrict__ out) {
  __shared__ float w[512];
  __shared__ float bb[2];
  const int t = threadIdx.x;
  w[t] = Wc2[t];
  w[t + 256] = Wc2[t + 256];
  if (t < 2) bb[t] = bc2[t];
  __syncthreads();
  const long row = (long)blockIdx.x * 256 + t;
  const f16* hr = hc + row * 256;
  float l0 = 0.f, l1 = 0.f;
  #pragma unroll 4
  for (int d0 = 0; d0 < 256; d0 += 8) {
    f16x8 v = *(const f16x8*)(hr + d0);
    #pragma unroll
    for (int j = 0; j < 8; ++j) {
      const float p = (float)v[j];
      l0 += p * w[(d0 + j) * 2];
      l1 += p * w[(d0 + j) * 2 + 1];
    }
  }
  l0 += bb[0];
  l1 += bb[1];
  const float mx = fmaxf(l0, l1);
  const float lse = mx + logf(expf(l0 - mx) + expf(l1 - mx));
  out[row * 2] = l0 - lse;
  out[row * 2 + 1] = l1 - lse;
}

extern "C" void kernel_launch(void* const* d_in, const int* in_sizes, int n_in,
                              void* d_out, int out_size, void* d_ws, size_t ws_size,
                              hipStream_t stream) {
  const float* x     = (const float*)d_in[0];   // [64,1024,256]
  const float* adj   = (const float*)d_in[1];   // [64,1024,1024]
  const float* W1    = (const float*)d_in[2];   // [512,512]
  const float* b1    = (const float*)d_in[3];
  const float* W2    = (const float*)d_in[4];   // [1024,512]
  const float* b2    = (const float*)d_in[5];
  const float* W3    = (const float*)d_in[6];   // [1024,256]
  const float* b3    = (const float*)d_in[7];
  const float* W4    = (const float*)d_in[8];   // [512,256]
  const float* b4    = (const float*)d_in[9];
  const float* Wc1   = (const float*)d_in[10];  // [256,256]
  const float* bc1   = (const float*)d_in[11];
  const float* alpha = (const float*)d_in[12];
  const float* Wc2   = (const float*)d_in[13];  // [256,2]
  const float* bc2   = (const float*)d_in[14];
  float* out = (float*)d_out;

  char* ws = (char*)d_ws;
  f16* adjB = (f16*)(ws + 0L);          // 134217728 B
  f16* xN   = (f16*)(ws + 134217728L);  // 33554432 B
  f16* xT   = (f16*)(ws + 167772160L);  // 33554432 B
  f16* agg  = (f16*)(ws + 201326592L);  // 67108864 B
  f16* hAN  = (f16*)(ws + 268435456L);  // 67108864 B  (h1, h3, hc)
  f16* hAT  = (f16*)(ws + 335544320L);  // 67108864 B  (h1T, h3T)
  f16* hBN  = (f16*)(ws + 402653184L);  // 67108864 B  (h2, h4)
  f16* hBT  = (f16*)(ws + 469762048L);  // 67108864 B  (h2T)
  f16* WT1  = (f16*)(ws + 536870912L);  // [512][512]
  f16* WT2  = (f16*)(ws + 537395200L);  // [512][1024]
  f16* WT3  = (f16*)(ws + 538443776L);  // [256][1024]
  f16* WT4  = (f16*)(ws + 538968064L);  // [256][512]
  f16* WTc1 = (f16*)(ws + 539230208L);  // [256][256]
  if (ws_size < (size_t)539361280L) return;

  const dim3 tb(32, 8, 1);

  cvt_f32_f16<<<2048, 256, 0, stream>>>(adj, adjB, 64L * 1024 * 1024);
  xprep<<<dim3(8, 32, 64), tb, 0, stream>>>(x, xN, xT, 1024, 256, 1024L * 256);
  transpose_cvt<<<dim3(16, 16, 1), tb, 0, stream>>>(W1, WT1, 512, 512, 0, 0);
  transpose_cvt<<<dim3(16, 32, 1), tb, 0, stream>>>(W2, WT2, 1024, 512, 0, 0);
  transpose_cvt<<<dim3(8, 32, 1), tb, 0, stream>>>(W3, WT3, 1024, 256, 0, 0);
  transpose_cvt<<<dim3(8, 16, 1), tb, 0, stream>>>(W4, WT4, 512, 256, 0, 0);
  transpose_cvt<<<dim3(8, 8, 1), tb, 0, stream>>>(Wc1, WTc1, 256, 256, 0, 0);

  // ---- L1: agg = adj @ x   (gx=4(bx), gy=1, z=64 -> nwg=256)
  gemm256<0, false, false><<<256, 512, 0, stream>>>(
      adjB, 1024, xT, 1024, 1024,
      nullptr, 0, nullptr, 0, 0,
      nullptr, nullptr, agg, 256, nullptr,
      1024L * 1024, 256L * 1024, 1024L * 256, 2, 0, 256);
  // h1 = relu(x@W1t + agg@W1b + b1)   (gx=256, gy=2 -> nwg=512)
  gemm256<1, true, true><<<512, 512, 0, stream>>>(
      xN, 256, WT1, 512, 256,
      agg, 256, WT1 + 256, 512, 256,
      b1, nullptr, hAN, 512, hAT, 0, 0, 0, 8, 1, 512);

  // ---- L2
  gemm256<0, false, false><<<512, 512, 0, stream>>>(
      adjB, 1024, hAT, 1024, 1024,
      nullptr, 0, nullptr, 0, 0,
      nullptr, nullptr, agg, 512, nullptr,
      1024L * 1024, 512L * 1024, 1024L * 512, 2, 1, 512);
  gemm256<1, true, true><<<512, 512, 0, stream>>>(
      hAN, 512, WT2, 1024, 512,
      agg, 512, WT2 + 512, 1024, 512,
      b2, nullptr, hBN, 512, hBT, 0, 0, 0, 8, 1, 512);

  // ---- L3
  gemm256<0, false, false><<<512, 512, 0, stream>>>(
      adjB, 1024, hBT, 1024, 1024,
      nullptr, 0, nullptr, 0, 0,
      nullptr, nullptr, agg, 512, nullptr,
      1024L * 1024, 512L * 1024, 1024L * 512, 2, 1, 512);
  gemm256<1, true, true><<<256, 512, 0, stream>>>(
      hBN, 512, WT3, 1024, 512,
      agg, 512, WT3 + 512, 1024, 512,
      b3, nullptr, hAN, 256, hAT, 0, 0, 0, 8, 0, 256);

  // ---- L4
  gemm256<0, false, false><<<256, 512, 0, stream>>>(
      adjB, 1024, hAT, 1024, 1024,
      nullptr, 0, nullptr, 0, 0,
      nullptr, nullptr, agg, 256, nullptr,
      1024L * 1024, 256L * 1024, 1024L * 256, 2, 0, 256);
  gemm256<1, true, false><<<256, 512, 0, stream>>>(
      hAN, 256, WT4, 512, 256,
      agg, 256, WT4 + 256, 512, 256,
      b4, nullptr, hBN, 256, nullptr, 0, 0, 0, 8, 0, 256);

  // ---- classifier
  gemm256<2, false, false><<<256, 512, 0, stream>>>(
      hBN, 256, WTc1, 256, 256,
      nullptr, 0, nullptr, 0, 0,
      bc1, alpha, hAN, 256, nullptr, 0, 0, 0, 8, 0, 256);

  logits_lsm<<<256, 256, 0, stream>>>(hAN, Wc2, bc2, out);
}

// Round 5
// 1084.913 us; speedup vs baseline: 1.0448x; 1.0330x over previous
//
#include <hip/hip_runtime.h>
#include <hip/hip_bf16.h>
#include <cmath>

typedef _Float16 f16;
typedef __attribute__((ext_vector_type(4))) _Float16 f16x4;
typedef __attribute__((ext_vector_type(8))) _Float16 f16x8;
typedef __attribute__((ext_vector_type(4))) float f32x4;

__device__ inline void gload_lds16(const f16* g, f16* l) {
  __builtin_amdgcn_global_load_lds(
      (const __attribute__((address_space(1))) unsigned int*)g,
      (__attribute__((address_space(3))) unsigned int*)l, 16, 0, 0);
}

// ---------------- f32 -> f16 convert (vectorized, grid-stride) ----------------
__global__ __launch_bounds__(256) void cvt_f32_f16(const float* __restrict__ in,
                                                   f16* __restrict__ out, long n) {
  long stride = (long)gridDim.x * 256 * 8;
  for (long i = ((long)blockIdx.x * 256 + threadIdx.x) * 8; i < n; i += stride) {
    float4 a = *(const float4*)(in + i);
    float4 b = *(const float4*)(in + i + 4);
    f16x8 o;
    o[0] = (f16)a.x; o[1] = (f16)a.y; o[2] = (f16)a.z; o[3] = (f16)a.w;
    o[4] = (f16)b.x; o[5] = (f16)b.y; o[6] = (f16)b.z; o[7] = (f16)b.w;
    *(f16x8*)(out + i) = o;
  }
}

// ----- fused x prep: read fp32 x once, emit xN (row-major f16) + xT (f16) -----
__global__ __launch_bounds__(256) void xprep(const float* __restrict__ in,
                                             f16* __restrict__ outN,
                                             f16* __restrict__ outT,
                                             int R, int C, long sIn) {
  in   += (long)blockIdx.z * sIn;
  outN += (long)blockIdx.z * sIn;
  outT += (long)blockIdx.z * sIn;
  __shared__ f16 t[32][34];
  const int tx = threadIdx.x, ty = threadIdx.y;
  const int c0 = blockIdx.x * 32, r0 = blockIdx.y * 32;
  #pragma unroll
  for (int j = 0; j < 32; j += 8) {
    const f16 v = (f16)in[(long)(r0 + ty + j) * C + (c0 + tx)];
    t[ty + j][tx] = v;
    outN[(long)(r0 + ty + j) * C + (c0 + tx)] = v;
  }
  __syncthreads();
  #pragma unroll
  for (int j = 0; j < 32; j += 8)
    outT[(long)(c0 + ty + j) * R + (r0 + tx)] = t[tx][ty + j];
}

// ------------- all 5 weight transposes in ONE dispatch (out[c][r]=in[r][c]) ---
__global__ __launch_bounds__(256) void wprep(const float* __restrict__ W1,
                                             const float* __restrict__ W2,
                                             const float* __restrict__ W3,
                                             const float* __restrict__ W4,
                                             const float* __restrict__ Wc1,
                                             f16* __restrict__ T1, f16* __restrict__ T2,
                                             f16* __restrict__ T3, f16* __restrict__ T4,
                                             f16* __restrict__ Tc1) {
  int b = blockIdx.x;
  const float* in; f16* out; int R, C;
  if (b < 256)       {          in = W1;  out = T1;  R = 512;  C = 512; }
  else if (b < 768)  { b -= 256;  in = W2;  out = T2;  R = 1024; C = 512; }
  else if (b < 1024) { b -= 768;  in = W3;  out = T3;  R = 1024; C = 256; }
  else if (b < 1152) { b -= 1024; in = W4;  out = T4;  R = 512;  C = 256; }
  else               { b -= 1152; in = Wc1; out = Tc1; R = 256;  C = 256; }
  const int nbx = C >> 5;
  const int c0 = (b % nbx) * 32, r0 = (b / nbx) * 32;
  __shared__ f16 t[32][34];
  const int tx = threadIdx.x & 31, ty = threadIdx.x >> 5;
  #pragma unroll
  for (int j = 0; j < 32; j += 8)
    t[ty + j][tx] = (f16)in[(long)(r0 + ty + j) * C + (c0 + tx)];
  __syncthreads();
  #pragma unroll
  for (int j = 0; j < 32; j += 8)
    out[(long)(c0 + ty + j) * R + (r0 + tx)] = t[tx][ty + j];
}

// ======== 128x128 NT GEMM, BK=32, 4 waves, 3 blocks/CU, counted vmcnt =========
// C = act(A1*B1^T [+ A2*B2^T] + bias). A [M,K] row-major, BT [N,K] row-major.
// Wave grid 2x2, per-wave 64x64 out (acc 64 VGPR). LDS 32KB double-buffered,
// chunk-XOR swizzle (chunk ^= (row>>1)&3). 1D grid, XCD-bijective, by-inner.
template <int ACT, bool DUAL, bool WRITE_T>
__global__ __launch_bounds__(256, 3) void gemm128(
    const f16* __restrict__ A1, int lda1,
    const f16* __restrict__ B1, int ldb1, int k1,
    const f16* __restrict__ A2, int lda2,
    const f16* __restrict__ B2, int ldb2, int k2,
    const float* __restrict__ bias, const float* __restrict__ alpha,
    f16* __restrict__ C, int ldc, f16* __restrict__ CT,
    long sA, long sB, long sC, int gxs, int gys, int nwg) {
  __shared__ __align__(16) f16 As[2][4096];  // [128 rows][32 k] per buf
  __shared__ __align__(16) f16 Bs[2][4096];
  const int wg = blockIdx.x;
  const int lid = (wg & 7) * (nwg >> 3) + (wg >> 3);
  const int by = lid & ((1 << gys) - 1);
  const int bx = (lid >> gys) & ((1 << gxs) - 1);
  const int z = lid >> (gxs + gys);

  const int tid = threadIdx.x;
  const f16* a1 = A1 + (long)z * sA;
  const f16* b1 = B1 + (long)z * sB;
  f16* pC = C + (long)z * sC;
  const int m0 = bx * 128, n0 = by * 128;
  const int lane = tid & 63, w = tid >> 6;
  const int wr = w >> 1, wc = w & 1;  // 2x2 wave grid
  const int lrow = lane & 15, kg = lane >> 4;
  const int NT1 = k1 >> 5;
  const int NT = NT1 + (DUAL ? (k2 >> 5) : 0);

  // staging: thread -> row tid>>2 (+64 per j), chunk slot tid&3; global chunk
  // pre-swizzled: LDS(r,c) = global(r, c ^ ((r>>1)&3)).
  const int srow = tid >> 2;
  const int cg = (tid & 3) ^ ((srow >> 1) & 3);
  const int ldst = (tid & 192) * 8;  // wave-uniform LDS dest part (elems)

  // frag-read: chunk = kg ^ ((row>>1)&3); row≡lrow (mod 16) for all m,n tiles
  const int swz = (lrow >> 1) & 3;
  const int ac = (kg ^ swz) * 8;
  const int arow = wr * 64 + lrow;
  const int brow = wc * 64 + lrow;

  f32x4 acc[4][4] = {};

  auto stage = [&](int kt, int buf) {
    const f16 *Ab, *Bb; int la, lb, kk;
    if (!DUAL || kt < NT1) { Ab = a1; Bb = b1; la = lda1; lb = ldb1; kk = kt << 5; }
    else { Ab = A2; Bb = B2; la = lda2; lb = ldb2; kk = (kt - NT1) << 5; }
    #pragma unroll
    for (int j = 0; j < 2; ++j)
      gload_lds16(Ab + (long)(m0 + srow + j * 64) * la + kk + cg * 8,
                  &As[buf][j * 2048 + ldst]);
    #pragma unroll
    for (int j = 0; j < 2; ++j)
      gload_lds16(Bb + (long)(n0 + srow + j * 64) * lb + kk + cg * 8,
                  &Bs[buf][j * 2048 + ldst]);
  };

  stage(0, 0);
  int buf = 0;
  for (int t = 0; t < NT; ++t) {
    // issue next tile's loads, then wait (counted) for THIS tile to land
    if (t + 1 < NT) {
      stage(t + 1, buf ^ 1);
      asm volatile("s_waitcnt vmcnt(4)" ::: "memory");
    } else {
      asm volatile("s_waitcnt vmcnt(0)" ::: "memory");
    }
    __builtin_amdgcn_s_barrier();
    f16x8 af[4], bf[4];
    #pragma unroll
    for (int m = 0; m < 4; ++m)
      af[m] = *(const f16x8*)&As[buf][(arow + m * 16) * 32 + ac];
    #pragma unroll
    for (int n = 0; n < 4; ++n)
      bf[n] = *(const f16x8*)&Bs[buf][(brow + n * 16) * 32 + ac];
    asm volatile("s_waitcnt lgkmcnt(0)" ::: "memory");
    __builtin_amdgcn_sched_barrier(0);
    __builtin_amdgcn_s_setprio(1);
    #pragma unroll
    for (int m = 0; m < 4; ++m)
      #pragma unroll
      for (int n = 0; n < 4; ++n)
        acc[m][n] = __builtin_amdgcn_mfma_f32_16x16x32_f16(af[m], bf[n], acc[m][n], 0, 0, 0);
    __builtin_amdgcn_s_setprio(0);
    if (t + 1 < NT) __builtin_amdgcn_s_barrier();  // readers done -> next stage may overwrite
    buf ^= 1;
  }

  // epilogue: C/D frag layout col(gn)=lane&15, row=(lane>>4)*4+r
  #pragma unroll
  for (int n = 0; n < 4; ++n) {
    const int gn = n0 + wc * 64 + n * 16 + lrow;
    const float bv = bias ? bias[gn] : 0.0f;
    const float av = (ACT == 2) ? alpha[gn] : 0.0f;
    #pragma unroll
    for (int m = 0; m < 4; ++m) {
      const int rg0 = m0 + wr * 64 + m * 16 + kg * 4;
      f16 tv[4];
      #pragma unroll
      for (int r = 0; r < 4; ++r) {
        float v = acc[m][n][r] + bv;
        if (ACT == 1) v = fmaxf(v, 0.0f);
        if (ACT == 2) v = (v > 0.0f) ? v : av * v;
        const f16 h = (f16)v;
        tv[r] = h;
        pC[(long)(rg0 + r) * ldc + gn] = h;
      }
      if (WRITE_T) {
        const int b = rg0 >> 10, node = rg0 & 1023;
        f16x4 pk;
        pk[0] = tv[0]; pk[1] = tv[1]; pk[2] = tv[2]; pk[3] = tv[3];
        *(f16x4*)&CT[((long)b * ldc + gn) * 1024 + node] = pk;
      }
    }
  }
}

// -------- final: logits = p @ Wc2 + bc2 ; out = log_softmax (fp32) ------------
__global__ __launch_bounds__(256) void logits_lsm(const f16* __restrict__ hc,
                                                  const float* __restrict__ Wc2,
                                                  const float* __restrict__ bc2,
                                                  float* __restrict__ out) {
  __shared__ float w[512];
  __shared__ float bb[2];
  const int t = threadIdx.x;
  w[t] = Wc2[t];
  w[t + 256] = Wc2[t + 256];
  if (t < 2) bb[t] = bc2[t];
  __syncthreads();
  const long row = (long)blockIdx.x * 256 + t;
  const f16* hr = hc + row * 256;
  float l0 = 0.f, l1 = 0.f;
  #pragma unroll 4
  for (int d0 = 0; d0 < 256; d0 += 8) {
    f16x8 v = *(const f16x8*)(hr + d0);
    #pragma unroll
    for (int j = 0; j < 8; ++j) {
      const float p = (float)v[j];
      l0 += p * w[(d0 + j) * 2];
      l1 += p * w[(d0 + j) * 2 + 1];
    }
  }
  l0 += bb[0];
  l1 += bb[1];
  const float mx = fmaxf(l0, l1);
  const float lse = mx + logf(expf(l0 - mx) + expf(l1 - mx));
  out[row * 2] = l0 - lse;
  out[row * 2 + 1] = l1 - lse;
}

extern "C" void kernel_launch(void* const* d_in, const int* in_sizes, int n_in,
                              void* d_out, int out_size, void* d_ws, size_t ws_size,
                              hipStream_t stream) {
  const float* x     = (const float*)d_in[0];   // [64,1024,256]
  const float* adj   = (const float*)d_in[1];   // [64,1024,1024]
  const float* W1    = (const float*)d_in[2];   // [512,512]
  const float* b1    = (const float*)d_in[3];
  const float* W2    = (const float*)d_in[4];   // [1024,512]
  const float* b2    = (const float*)d_in[5];
  const float* W3    = (const float*)d_in[6];   // [1024,256]
  const float* b3    = (const float*)d_in[7];
  const float* W4    = (const float*)d_in[8];   // [512,256]
  const float* b4    = (const float*)d_in[9];
  const float* Wc1   = (const float*)d_in[10];  // [256,256]
  const float* bc1   = (const float*)d_in[11];
  const float* alpha = (const float*)d_in[12];
  const float* Wc2   = (const float*)d_in[13];  // [256,2]
  const float* bc2   = (const float*)d_in[14];
  float* out = (float*)d_out;

  char* ws = (char*)d_ws;
  f16* adjB = (f16*)(ws + 0L);          // 134217728 B
  f16* xN   = (f16*)(ws + 134217728L);  // 33554432 B
  f16* xT   = (f16*)(ws + 167772160L);  // 33554432 B
  f16* agg  = (f16*)(ws + 201326592L);  // 67108864 B
  f16* hAN  = (f16*)(ws + 268435456L);  // 67108864 B  (h1, h3, hc)
  f16* hAT  = (f16*)(ws + 335544320L);  // 67108864 B  (h1T, h3T)
  f16* hBN  = (f16*)(ws + 402653184L);  // 67108864 B  (h2, h4)
  f16* hBT  = (f16*)(ws + 469762048L);  // 67108864 B  (h2T)
  f16* WT1  = (f16*)(ws + 536870912L);  // [512][512]
  f16* WT2  = (f16*)(ws + 537395200L);  // [512][1024]
  f16* WT3  = (f16*)(ws + 538443776L);  // [256][1024]
  f16* WT4  = (f16*)(ws + 538968064L);  // [256][512]
  f16* WTc1 = (f16*)(ws + 539230208L);  // [256][256]
  if (ws_size < (size_t)539361280L) return;

  cvt_f32_f16<<<2048, 256, 0, stream>>>(adj, adjB, 64L * 1024 * 1024);
  xprep<<<dim3(8, 32, 64), dim3(32, 8, 1), 0, stream>>>(x, xN, xT, 1024, 256, 1024L * 256);
  wprep<<<1216, 256, 0, stream>>>(W1, W2, W3, W4, Wc1, WT1, WT2, WT3, WT4, WTc1);

  // ---- L1: agg = adj @ x   (bx=8, by=2, z=64 -> nwg=1024)
  gemm128<0, false, false><<<1024, 256, 0, stream>>>(
      adjB, 1024, xT, 1024, 1024,
      nullptr, 0, nullptr, 0, 0,
      nullptr, nullptr, agg, 256, nullptr,
      1024L * 1024, 256L * 1024, 1024L * 256, 3, 1, 1024);
  // h1 = relu(x@W1t + agg@W1b + b1)   (bx=512, by=4 -> nwg=2048)
  gemm128<1, true, true><<<2048, 256, 0, stream>>>(
      xN, 256, WT1, 512, 256,
      agg, 256, WT1 + 256, 512, 256,
      b1, nullptr, hAN, 512, hAT, 0, 0, 0, 9, 2, 2048);

  // ---- L2
  gemm128<0, false, false><<<2048, 256, 0, stream>>>(
      adjB, 1024, hAT, 1024, 1024,
      nullptr, 0, nullptr, 0, 0,
      nullptr, nullptr, agg, 512, nullptr,
      1024L * 1024, 512L * 1024, 1024L * 512, 3, 2, 2048);
  gemm128<1, true, true><<<2048, 256, 0, stream>>>(
      hAN, 512, WT2, 1024, 512,
      agg, 512, WT2 + 512, 1024, 512,
      b2, nullptr, hBN, 512, hBT, 0, 0, 0, 9, 2, 2048);

  // ---- L3
  gemm128<0, false, false><<<2048, 256, 0, stream>>>(
      adjB, 1024, hBT, 1024, 1024,
      nullptr, 0, nullptr, 0, 0,
      nullptr, nullptr, agg, 512, nullptr,
      1024L * 1024, 512L * 1024, 1024L * 512, 3, 2, 2048);
  gemm128<1, true, true><<<1024, 256, 0, stream>>>(
      hBN, 512, WT3, 1024, 512,
      agg, 512, WT3 + 512, 1024, 512,
      b3, nullptr, hAN, 256, hAT, 0, 0, 0, 9, 1, 1024);

  // ---- L4
  gemm128<0, false, false><<<1024, 256, 0, stream>>>(
      adjB, 1024, hAT, 1024, 1024,
      nullptr, 0, nullptr, 0, 0,
      nullptr, nullptr, agg, 256, nullptr,
      1024L * 1024, 256L * 1024, 1024L * 256, 3, 1, 1024);
  gemm128<1, true, false><<<1024, 256, 0, stream>>>(
      hAN, 256, WT4, 512, 256,
      agg, 256, WT4 + 256, 512, 256,
      b4, nullptr, hBN, 256, nullptr, 0, 0, 0, 9, 1, 1024);

  // ---- classifier
  gemm128<2, false, false><<<1024, 256, 0, stream>>>(
      hBN, 256, WTc1, 256, 256,
      nullptr, 0, nullptr, 0, 0,
      bc1, alpha, hAN, 256, nullptr, 0, 0, 0, 9, 1, 1024);

  logits_lsm<<<256, 256, 0, stream>>>(hAN, Wc2, bc2, out);
}